// Round 1
// baseline (1099.929 us; speedup 1.0000x reference)
//
#include <hip/hip_runtime.h>
#include <hip/hip_bf16.h>
#include <math.h>

#define NND 6144
#define NED 12288
static constexpr float EPS_BN = 1e-5f;

// ---------------- ws layout (float offsets) ----------------
#define HN_OFF    0         // [N,32]
#define HE_OFF    196608    // [N,2]
#define PRE_OFF   208896    // [N]
#define STATS_OFF 215040    // [64]  (sum0[16] sq0[16] sum1[16] sq1[16])
#define Y_OFF     215104    // [N,32]   Y0 then Y1
#define T0_OFF    411712    // [N,32] H  then [E,16] Zc0
#define T1_OFF    608320    // [E,16] Zt0 then Zc1
#define Z0_OFF    804928    // [E]
#define Z1_OFF    817216    // [E]
#define U_OFF     829504    // [E]
#define S_OFF     841792    // [E]

__global__ void init_ws(float* __restrict__ p, int n) {
  int i = blockIdx.x * blockDim.x + threadIdx.x;
  if (i < n) p[i] = 0.f;
}

// C[m,:] = X[m,:] @ W[OC,IC]^T (+bias). One thread per row m.
template<int IC, int OC>
__global__ void small_mm(const float* __restrict__ X, const float* __restrict__ W,
                         const float* __restrict__ bias, float* __restrict__ C, int M) {
  int m = blockIdx.x * blockDim.x + threadIdx.x;
  if (m >= M) return;
  float x[IC];
  #pragma unroll
  for (int k = 0; k < IC; k += 4) {
    float4 v = *reinterpret_cast<const float4*>(X + (size_t)m * IC + k);
    x[k] = v.x; x[k+1] = v.y; x[k+2] = v.z; x[k+3] = v.w;
  }
  for (int oc = 0; oc < OC; ++oc) {
    float s = bias ? bias[oc] : 0.f;
    #pragma unroll
    for (int k = 0; k < IC; ++k) s += x[k] * W[oc * IC + k];
    C[(size_t)m * OC + oc] = s;
  }
}

// out[M,NC] = A[M,K] @ Y[K,NC], optional +bias[NC], optional relu.
// block = 256 (4 waves). Wave: cg = w%CG (16-col group), rg = w/CG (4-row group).
// Lane owns k = kb + lane*4 .. +3. acc[4 rows][16 cols]; butterfly-reduce over 64 lanes.
template<int NC, int CG, bool RELU>
__global__ __launch_bounds__(256, 2)
void big_mm(const float* __restrict__ A, const float* __restrict__ Y,
            const float* __restrict__ bias, float* __restrict__ out, int K) {
  constexpr int RG = 4 / CG;
  constexpr int ROWS = RG * 4;
  const int lane = threadIdx.x & 63;
  const int w = threadIdx.x >> 6;
  const int cg = w % CG, rg = w / CG;
  const int r0 = blockIdx.x * ROWS + rg * 4;
  const int c0 = cg * 16;

  float acc[4][16];
  #pragma unroll
  for (int r = 0; r < 4; ++r)
    #pragma unroll
    for (int c = 0; c < 16; ++c) acc[r][c] = 0.f;

  for (int kb = 0; kb < K; kb += 256) {
    const int k = kb + lane * 4;
    float a_s[4][4];
    #pragma unroll
    for (int r = 0; r < 4; ++r) {
      float4 v = *reinterpret_cast<const float4*>(A + (size_t)(r0 + r) * K + k);
      a_s[r][0] = v.x; a_s[r][1] = v.y; a_s[r][2] = v.z; a_s[r][3] = v.w;
    }
    #pragma unroll
    for (int kk = 0; kk < 4; ++kk) {
      const float* yp = Y + (size_t)(k + kk) * NC + c0;
      float4 y0 = *reinterpret_cast<const float4*>(yp + 0);
      float4 y1 = *reinterpret_cast<const float4*>(yp + 4);
      float4 y2 = *reinterpret_cast<const float4*>(yp + 8);
      float4 y3 = *reinterpret_cast<const float4*>(yp + 12);
      float ys[16] = {y0.x,y0.y,y0.z,y0.w, y1.x,y1.y,y1.z,y1.w,
                      y2.x,y2.y,y2.z,y2.w, y3.x,y3.y,y3.z,y3.w};
      #pragma unroll
      for (int r = 0; r < 4; ++r) {
        const float av = a_s[r][kk];
        #pragma unroll
        for (int c = 0; c < 16; ++c) acc[r][c] += av * ys[c];
      }
    }
  }

  // reduce each acc over the 64 lanes
  #pragma unroll
  for (int r = 0; r < 4; ++r)
    #pragma unroll
    for (int c = 0; c < 16; ++c)
      #pragma unroll
      for (int m = 1; m < 64; m <<= 1)
        acc[r][c] += __shfl_xor(acc[r][c], m, 64);

  // lane l owns (row l>>4, col l&15); static selection (no dynamic indexing)
  float keep = 0.f;
  #pragma unroll
  for (int r = 0; r < 4; ++r)
    #pragma unroll
    for (int c = 0; c < 16; ++c)
      if (lane == r * 16 + c) keep = acc[r][c];

  const int rsel = lane >> 4, csel = lane & 15;
  float v = keep + (bias ? bias[c0 + csel] : 0.f);
  if (RELU) v = fmaxf(v, 0.f);
  out[(size_t)(r0 + rsel) * NC + c0 + csel] = v;
}

// MODE 0: o1[row]=M·za (u), o2[row]=rowsum (s).  MODE 1: o1[row*2]=M·za, o1[row*2+1]=M·zb.
template<int MODE>
__global__ __launch_bounds__(256, 2)
void rowpass(const float* __restrict__ Mt, const float* __restrict__ za,
             const float* __restrict__ zb, float* __restrict__ o1,
             float* __restrict__ o2, int K) {
  const int lane = threadIdx.x & 63;
  const int row = blockIdx.x * 4 + (threadIdx.x >> 6);
  const float* mp = Mt + (size_t)row * K;
  float accA = 0.f, accB = 0.f;
  for (int kb = 0; kb < K; kb += 256) {
    const int k = kb + lane * 4;
    float4 a = *reinterpret_cast<const float4*>(mp + k);
    float4 z = *reinterpret_cast<const float4*>(za + k);
    if (MODE == 0) {
      accA += a.x*z.x + a.y*z.y + a.z*z.z + a.w*z.w;
      accB += a.x + a.y + a.z + a.w;
    } else {
      float4 z2 = *reinterpret_cast<const float4*>(zb + k);
      accA += a.x*z.x + a.y*z.y + a.z*z.z + a.w*z.w;
      accB += a.x*z2.x + a.y*z2.y + a.z*z2.z + a.w*z2.w;
    }
  }
  #pragma unroll
  for (int m = 1; m < 64; m <<= 1) {
    accA += __shfl_xor(accA, m, 64);
    accB += __shfl_xor(accB, m, 64);
  }
  if (lane == 0) {
    if (MODE == 0) { o1[row] = accA; o2[row] = accB; }
    else { o1[row * 2] = accA; o1[row * 2 + 1] = accB; }
  }
}

// per-channel sum & sumsq over E rows of Zc[E,16] -> stats[0:16]=sum, [16:32]=sumsq
__global__ void bn_stats(const float* __restrict__ Zc, float* __restrict__ stats) {
  const int e = blockIdx.x * blockDim.x + threadIdx.x;
  const int lane = threadIdx.x & 63;
  float s[16], q[16];
  #pragma unroll
  for (int c = 0; c < 16; c += 4) {
    float4 v = *reinterpret_cast<const float4*>(Zc + (size_t)e * 16 + c);
    s[c]=v.x; s[c+1]=v.y; s[c+2]=v.z; s[c+3]=v.w;
    q[c]=v.x*v.x; q[c+1]=v.y*v.y; q[c+2]=v.z*v.z; q[c+3]=v.w*v.w;
  }
  #pragma unroll
  for (int c = 0; c < 16; ++c)
    #pragma unroll
    for (int m = 1; m < 64; m <<= 1) {
      s[c] += __shfl_xor(s[c], m, 64);
      q[c] += __shfl_xor(q[c], m, 64);
    }
  if (lane == 0) {
    #pragma unroll
    for (int c = 0; c < 16; ++c) {
      atomicAdd(stats + c, s[c]);
      atomicAdd(stats + 16 + c, q[c]);
    }
  }
}

// Z[e] = relu(max_c(g[c]*(x-m)*rsqrt(v+eps)+beta[c]))
__global__ void bn_max(const float* __restrict__ Zc, const float* __restrict__ stats,
                       const float* __restrict__ g, const float* __restrict__ beta,
                       float* __restrict__ Z, int E) {
  const int e = blockIdx.x * blockDim.x + threadIdx.x;
  if (e >= E) return;
  const float invE = 1.f / (float)E;
  float best = -3.4e38f;
  #pragma unroll
  for (int c = 0; c < 16; ++c) {
    float m = stats[c] * invE;
    float var = stats[16 + c] * invE - m * m;
    float sc = g[c] * rsqrtf(var + EPS_BN);
    float sh = beta[c] - m * sc;
    float x = Zc[(size_t)e * 16 + c];
    best = fmaxf(best, x * sc + sh);
  }
  Z[e] = fmaxf(best, 0.f);
}

// Zc1[e,c] = W1[c]*u[e] + b1[c]*s[e]
__global__ void make_zc1(const float* __restrict__ u, const float* __restrict__ s,
                         const float* __restrict__ W1, const float* __restrict__ b1,
                         float* __restrict__ Zc1, int E) {
  const int e = blockIdx.x * blockDim.x + threadIdx.x;
  if (e >= E) return;
  const float uu = u[e], ss = s[e];
  #pragma unroll
  for (int c = 0; c < 16; ++c) Zc1[(size_t)e * 16 + c] = W1[c] * uu + b1[c] * ss;
}

// pre[n] += sum_{j in chunk} relu(Hcat[n]·fc1W[j] + fc1b[j]) * fc2W[j]
// thread owns 4 rows (H rows in 136 VGPRs); j uniform across the wave.
__global__ __launch_bounds__(256, 2)
void head(const float* __restrict__ Hn, const float* __restrict__ he,
          const float* __restrict__ W1, const float* __restrict__ b1,
          const float* __restrict__ w2, float* __restrict__ pre) {
  const int t = threadIdx.x;
  const int nb = blockIdx.x;      // 6 blocks of 1024 rows
  const int jb = blockIdx.y;      // 64 chunks of 192 j
  int n[4];
  float h[4][34];
  float acc[4] = {0.f, 0.f, 0.f, 0.f};
  #pragma unroll
  for (int i = 0; i < 4; ++i) {
    n[i] = nb * 1024 + i * 256 + t;
    #pragma unroll
    for (int k = 0; k < 32; k += 4) {
      float4 v = *reinterpret_cast<const float4*>(Hn + (size_t)n[i] * 32 + k);
      h[i][k] = v.x; h[i][k+1] = v.y; h[i][k+2] = v.z; h[i][k+3] = v.w;
    }
    h[i][32] = he[n[i] * 2];
    h[i][33] = he[n[i] * 2 + 1];
  }
  const int j0 = jb * 192;
  for (int j = j0; j < j0 + 192; ++j) {
    const float* wp = W1 + (size_t)j * 34;
    const float bj = b1[j], vj = w2[j];
    float s0 = bj, s1 = bj, s2 = bj, s3 = bj;
    #pragma unroll
    for (int k = 0; k < 34; ++k) {
      const float wk = wp[k];
      s0 += h[0][k] * wk; s1 += h[1][k] * wk;
      s2 += h[2][k] * wk; s3 += h[3][k] * wk;
    }
    acc[0] += fmaxf(s0, 0.f) * vj;
    acc[1] += fmaxf(s1, 0.f) * vj;
    acc[2] += fmaxf(s2, 0.f) * vj;
    acc[3] += fmaxf(s3, 0.f) * vj;
  }
  #pragma unroll
  for (int i = 0; i < 4; ++i) atomicAdd(pre + n[i], acc[i]);
}

__global__ void final_k(const float* __restrict__ pre, const float* __restrict__ b2,
                        float* __restrict__ out, int Nn) {
  const int i = blockIdx.x * blockDim.x + threadIdx.x;
  if (i < Nn) out[i] = 1.f / (1.f + expf(-(pre[i] + b2[0])));
}

extern "C" void kernel_launch(void* const* d_in, const int* in_sizes, int n_in,
                              void* d_out, int out_size, void* d_ws, size_t ws_size,
                              hipStream_t stream) {
  const float* X_n   = (const float*)d_in[0];
  const float* X_e   = (const float*)d_in[1];
  const float* A     = (const float*)d_in[2];
  const float* L1    = (const float*)d_in[3];
  const float* B1    = (const float*)d_in[4];
  const float* gW0   = (const float*)d_in[5];
  const float* gb0   = (const float*)d_in[6];
  const float* gW1   = (const float*)d_in[7];
  const float* gb1   = (const float*)d_in[8];
  const float* tW0   = (const float*)d_in[9];
  const float* tb0   = (const float*)d_in[10];
  const float* bng0  = (const float*)d_in[11];
  const float* bnb0  = (const float*)d_in[12];
  const float* tW1   = (const float*)d_in[13];
  const float* tb1   = (const float*)d_in[14];
  const float* bng1  = (const float*)d_in[15];
  const float* bnb1  = (const float*)d_in[16];
  const float* fc1W  = (const float*)d_in[17];
  const float* fc1b  = (const float*)d_in[18];
  const float* fc2W  = (const float*)d_in[19];
  const float* fc2b  = (const float*)d_in[20];

  float* ws   = (float*)d_ws;
  float* Hn   = ws + HN_OFF;
  float* he   = ws + HE_OFF;
  float* pre  = ws + PRE_OFF;
  float* st   = ws + STATS_OFF;
  float* Y    = ws + Y_OFF;
  float* T0   = ws + T0_OFF;
  float* T1   = ws + T1_OFF;
  float* Z0   = ws + Z0_OFF;
  float* Z1   = ws + Z1_OFF;
  float* u    = ws + U_OFF;
  float* s    = ws + S_OFF;
  float* out  = (float*)d_out;

  // zero pre + stats (contiguous 6208 floats)
  init_ws<<<25, 256, 0, stream>>>(ws + PRE_OFF, 6208);

  // ---- GNN ----
  small_mm<32, 32><<<24, 256, 0, stream>>>(X_n, gW0, nullptr, Y, NND);          // Y0 = X_n @ W0^T
  big_mm<32, 2, true><<<768, 256, 0, stream>>>(A, Y, gb0, T0, NND);             // H = relu(A@Y0+b0)
  small_mm<32, 32><<<24, 256, 0, stream>>>(T0, gW1, nullptr, Y, NND);           // Y1 = H @ W1^T
  big_mm<32, 2, true><<<768, 256, 0, stream>>>(A, Y, gb1, Hn, NND);             // Hn = relu(A@Y1+b1)

  // ---- HoSC layer 0 ----
  small_mm<16, 16><<<48, 256, 0, stream>>>(X_e, tW0, tb0, T1, NED);             // Zt0
  big_mm<16, 1, false><<<768, 256, 0, stream>>>(L1, T1, nullptr, T0, NED);      // Zc0 = L1@Zt0
  bn_stats<<<48, 256, 0, stream>>>(T0, st);
  bn_max<<<48, 256, 0, stream>>>(T0, st, bng0, bnb0, Z0, NED);

  // ---- HoSC layer 1 (rank-1 collapse: u = L1@Z0, s = L1@1) ----
  rowpass<0><<<3072, 256, 0, stream>>>(L1, Z0, nullptr, u, s, NED);
  make_zc1<<<48, 256, 0, stream>>>(u, s, tW1, tb1, T1, NED);
  bn_stats<<<48, 256, 0, stream>>>(T1, st + 32);
  bn_max<<<48, 256, 0, stream>>>(T1, st + 32, bng1, bnb1, Z1, NED);

  // ---- H_e = B1 @ [Z0 Z1] ----
  rowpass<1><<<1536, 256, 0, stream>>>(B1, Z0, Z1, he, nullptr, NED);

  // ---- head ----
  head<<<dim3(6, 64), 256, 0, stream>>>(Hn, he, fc1W, fc1b, fc2W, pre);
  final_k<<<24, 256, 0, stream>>>(pre, fc2b, out, NND);
}

// Round 2
// 768.439 us; speedup vs baseline: 1.4314x; 1.4314x over previous
//
#include <hip/hip_runtime.h>
#include <hip/hip_bf16.h>
#include <math.h>

#define NND 6144
#define NED 12288
static constexpr float EPS_BN = 1e-5f;

// ---------------- ws layout (float offsets) ----------------
#define HN_OFF    0         // [N,32] Hn
#define HE_OFF    196608    // [N,2]
#define PRE_OFF   208896    // [N]
#define STATS_OFF 215040    // [64]  (sum0[16] sq0[16] sum1[16] sq1[16])
#define Y_OFF     215104    // YT [32,N] for GNN (196608 floats)
#define T0_OFF    411712    // H [N,32], then Zc0 [E,16]
#define T1_OFF    608320    // ZtT [16,E], then Zc1 [E,16]
#define Z0_OFF    804928    // [E]
#define Z1_OFF    817216    // [E]
#define U_OFF     829504    // [E]
#define S_OFF     841792    // [E]

__global__ void init_ws(float* __restrict__ p, int n) {
  int i = blockIdx.x * blockDim.x + threadIdx.x;
  if (i < n) p[i] = 0.f;
}

// CT[oc, m] = X[m,:] @ W[oc,:] (+bias). One thread per row m, TRANSPOSED output
// (coalesced per-oc writes) so big_mm can read Y^T rows coalesced.
template<int IC, int OC>
__global__ void small_mm_T(const float* __restrict__ X, const float* __restrict__ W,
                           const float* __restrict__ bias, float* __restrict__ CT, int M) {
  int m = blockIdx.x * blockDim.x + threadIdx.x;
  if (m >= M) return;
  float x[IC];
  #pragma unroll
  for (int k = 0; k < IC; k += 4) {
    float4 v = *reinterpret_cast<const float4*>(X + (size_t)m * IC + k);
    x[k] = v.x; x[k+1] = v.y; x[k+2] = v.z; x[k+3] = v.w;
  }
  #pragma unroll
  for (int oc = 0; oc < OC; ++oc) {
    float s = bias ? bias[oc] : 0.f;
    #pragma unroll
    for (int k = 0; k < IC; ++k) s = fmaf(x[k], W[oc * IC + k], s);
    CT[(size_t)oc * M + m] = s;
  }
}

// out[M,NC] = A[M,K] @ YT[NC,K]^T, optional +bias, relu, fused BN-stats.
// block=256 (4 waves). Wave: cg=w%CG (16-col group), rg=w/CG (4-row group).
// Lane owns k = kb + lane*4..+3; ALL loads coalesced. Compact 63-shfl reduce.
template<int NC, int CG, bool RELU, bool STATS>
__global__ __launch_bounds__(256, 2)
void big_mm(const float* __restrict__ A, const float* __restrict__ YT,
            const float* __restrict__ bias, float* __restrict__ out,
            float* __restrict__ stats, int K) {
  constexpr int RG = 4 / CG;
  constexpr int ROWS = RG * 4;
  const int lane = threadIdx.x & 63;
  const int w = threadIdx.x >> 6;
  const int cg = w % CG, rg = w / CG;
  const int r0 = blockIdx.x * ROWS + rg * 4;
  const int c0 = cg * 16;

  const float* ap[4];
  #pragma unroll
  for (int r = 0; r < 4; ++r) ap[r] = A + (size_t)(r0 + r) * K;
  const float* yp[16];
  #pragma unroll
  for (int c = 0; c < 16; ++c) yp[c] = YT + (size_t)(c0 + c) * K;

  float acc[4][16];
  #pragma unroll
  for (int r = 0; r < 4; ++r)
    #pragma unroll
    for (int c = 0; c < 16; ++c) acc[r][c] = 0.f;

  for (int kb = 0; kb < K; kb += 256) {
    const int k = kb + lane * 4;
    float4 av[4];
    #pragma unroll
    for (int r = 0; r < 4; ++r) av[r] = *reinterpret_cast<const float4*>(ap[r] + k);
    float4 yv[16];
    #pragma unroll
    for (int c = 0; c < 16; ++c) yv[c] = *reinterpret_cast<const float4*>(yp[c] + k);
    #pragma unroll
    for (int c = 0; c < 16; ++c) {
      const float4 y = yv[c];
      #pragma unroll
      for (int r = 0; r < 4; ++r) {
        acc[r][c] = fmaf(av[r].x, y.x, acc[r][c]);
        acc[r][c] = fmaf(av[r].y, y.y, acc[r][c]);
        acc[r][c] = fmaf(av[r].z, y.z, acc[r][c]);
        acc[r][c] = fmaf(av[r].w, y.w, acc[r][c]);
      }
    }
  }

  // Compact cross-lane reduce: 64 values x 64 lanes -> lane l holds value l.
  // Value index v = r*16+c; step bit b: lane keeps values with v_b == lane_b.
  float wv[64];
  #pragma unroll
  for (int r = 0; r < 4; ++r)
    #pragma unroll
    for (int c = 0; c < 16; ++c) wv[r * 16 + c] = acc[r][c];
  #pragma unroll
  for (int b = 5; b >= 0; --b) {
    const int m = 1 << b;
    const bool hi = (lane & m) != 0;
    #pragma unroll
    for (int i = 0; i < (1 << b); ++i) {
      float a  = wv[i];            // value with bit b == 0
      float bb = wv[i + (1 << b)]; // value with bit b == 1
      float send = hi ? a : bb;
      float recv = __shfl_xor(send, m, 64);
      wv[i] = (hi ? bb : a) + recv;
    }
  }

  const int rsel = lane >> 4, csel = lane & 15;
  float v = wv[0] + (bias ? bias[c0 + csel] : 0.f);
  if (RELU) v = fmaxf(v, 0.f);
  out[(size_t)(r0 + rsel) * NC + c0 + csel] = v;

  if (STATS) {
    __shared__ float sst[32];
    if (threadIdx.x < 32) sst[threadIdx.x] = 0.f;
    __syncthreads();
    float sv = v, qv = v * v;
    sv += __shfl_xor(sv, 16, 64); sv += __shfl_xor(sv, 32, 64);
    qv += __shfl_xor(qv, 16, 64); qv += __shfl_xor(qv, 32, 64);
    if (lane < 16) { atomicAdd(&sst[csel], sv); atomicAdd(&sst[16 + csel], qv); }
    __syncthreads();
    if (threadIdx.x < 32) atomicAdd(stats + threadIdx.x, sst[threadIdx.x]);
  }
}

// MODE 0: o1[row]=M·za, o2[row]=rowsum.  MODE 1: o1[row*2]=M·za, o1[row*2+1]=M·zb.
template<int MODE>
__global__ __launch_bounds__(256, 2)
void rowpass(const float* __restrict__ Mt, const float* __restrict__ za,
             const float* __restrict__ zb, float* __restrict__ o1,
             float* __restrict__ o2, int K) {
  const int lane = threadIdx.x & 63;
  const int row = blockIdx.x * 4 + (threadIdx.x >> 6);
  const float* mp = Mt + (size_t)row * K;
  float accA = 0.f, accB = 0.f;
  for (int kb = 0; kb < K; kb += 256) {
    const int k = kb + lane * 4;
    float4 a = *reinterpret_cast<const float4*>(mp + k);
    float4 z = *reinterpret_cast<const float4*>(za + k);
    if (MODE == 0) {
      accA += a.x*z.x + a.y*z.y + a.z*z.z + a.w*z.w;
      accB += a.x + a.y + a.z + a.w;
    } else {
      float4 z2 = *reinterpret_cast<const float4*>(zb + k);
      accA += a.x*z.x + a.y*z.y + a.z*z.z + a.w*z.w;
      accB += a.x*z2.x + a.y*z2.y + a.z*z2.z + a.w*z2.w;
    }
  }
  #pragma unroll
  for (int m = 1; m < 64; m <<= 1) {
    accA += __shfl_xor(accA, m, 64);
    accB += __shfl_xor(accB, m, 64);
  }
  if (lane == 0) {
    if (MODE == 0) { o1[row] = accA; o2[row] = accB; }
    else { o1[row * 2] = accA; o1[row * 2 + 1] = accB; }
  }
}

// Z[e] = relu(max_c(g[c]*(x-m)*rsqrt(v+eps)+beta[c]))
__global__ void bn_max(const float* __restrict__ Zc, const float* __restrict__ stats,
                       const float* __restrict__ g, const float* __restrict__ beta,
                       float* __restrict__ Z, int E) {
  const int e = blockIdx.x * blockDim.x + threadIdx.x;
  if (e >= E) return;
  const float invE = 1.f / (float)E;
  float best = -3.4e38f;
  #pragma unroll
  for (int c = 0; c < 16; ++c) {
    float m = stats[c] * invE;
    float var = stats[16 + c] * invE - m * m;
    float sc = g[c] * rsqrtf(var + EPS_BN);
    float sh = beta[c] - m * sc;
    float x = Zc[(size_t)e * 16 + c];
    best = fmaxf(best, fmaf(x, sc, sh));
  }
  Z[e] = fmaxf(best, 0.f);
}

// Zc1[e,c] = W1[c]*u[e] + b1[c]*s[e], fused per-channel stats accumulation.
__global__ void make_zc1_stats(const float* __restrict__ u, const float* __restrict__ s,
                               const float* __restrict__ W1, const float* __restrict__ b1,
                               float* __restrict__ Zc1, float* __restrict__ stats, int E) {
  const int e = blockIdx.x * blockDim.x + threadIdx.x;
  const int lane = threadIdx.x & 63;
  const float uu = u[e], ss = s[e];
  float sm[16], sq[16];
  #pragma unroll
  for (int c = 0; c < 16; ++c) {
    float v = fmaf(W1[c], uu, b1[c] * ss);
    Zc1[(size_t)e * 16 + c] = v;
    sm[c] = v; sq[c] = v * v;
  }
  #pragma unroll
  for (int c = 0; c < 16; ++c)
    #pragma unroll
    for (int m = 1; m < 64; m <<= 1) {
      sm[c] += __shfl_xor(sm[c], m, 64);
      sq[c] += __shfl_xor(sq[c], m, 64);
    }
  if (lane == 0) {
    #pragma unroll
    for (int c = 0; c < 16; ++c) {
      atomicAdd(stats + c, sm[c]);
      atomicAdd(stats + 16 + c, sq[c]);
    }
  }
}

// pre[n] += sum_{j in chunk} relu(Hcat[n]·fc1W[j] + fc1b[j]) * fc2W[j]
__global__ __launch_bounds__(256, 2)
void head(const float* __restrict__ Hn, const float* __restrict__ he,
          const float* __restrict__ W1, const float* __restrict__ b1,
          const float* __restrict__ w2, float* __restrict__ pre) {
  const int t = threadIdx.x;
  const int nb = blockIdx.x;      // 6 blocks of 1024 rows
  const int jb = blockIdx.y;      // 64 chunks of 192 j
  int n[4];
  float h[4][34];
  float acc[4] = {0.f, 0.f, 0.f, 0.f};
  #pragma unroll
  for (int i = 0; i < 4; ++i) {
    n[i] = nb * 1024 + i * 256 + t;
    #pragma unroll
    for (int k = 0; k < 32; k += 4) {
      float4 v = *reinterpret_cast<const float4*>(Hn + (size_t)n[i] * 32 + k);
      h[i][k] = v.x; h[i][k+1] = v.y; h[i][k+2] = v.z; h[i][k+3] = v.w;
    }
    h[i][32] = he[n[i] * 2];
    h[i][33] = he[n[i] * 2 + 1];
  }
  const int j0 = jb * 192;
  for (int j = j0; j < j0 + 192; ++j) {
    const float* wp = W1 + (size_t)j * 34;
    const float bj = b1[j], vj = w2[j];
    float s0 = bj, s1 = bj, s2 = bj, s3 = bj;
    #pragma unroll
    for (int k = 0; k < 34; ++k) {
      const float wk = wp[k];
      s0 = fmaf(h[0][k], wk, s0); s1 = fmaf(h[1][k], wk, s1);
      s2 = fmaf(h[2][k], wk, s2); s3 = fmaf(h[3][k], wk, s3);
    }
    acc[0] += fmaxf(s0, 0.f) * vj;
    acc[1] += fmaxf(s1, 0.f) * vj;
    acc[2] += fmaxf(s2, 0.f) * vj;
    acc[3] += fmaxf(s3, 0.f) * vj;
  }
  #pragma unroll
  for (int i = 0; i < 4; ++i) atomicAdd(pre + n[i], acc[i]);
}

__global__ void final_k(const float* __restrict__ pre, const float* __restrict__ b2,
                        float* __restrict__ out, int Nn) {
  const int i = blockIdx.x * blockDim.x + threadIdx.x;
  if (i < Nn) out[i] = 1.f / (1.f + expf(-(pre[i] + b2[0])));
}

extern "C" void kernel_launch(void* const* d_in, const int* in_sizes, int n_in,
                              void* d_out, int out_size, void* d_ws, size_t ws_size,
                              hipStream_t stream) {
  const float* X_n   = (const float*)d_in[0];
  const float* X_e   = (const float*)d_in[1];
  const float* A     = (const float*)d_in[2];
  const float* L1    = (const float*)d_in[3];
  const float* B1    = (const float*)d_in[4];
  const float* gW0   = (const float*)d_in[5];
  const float* gb0   = (const float*)d_in[6];
  const float* gW1   = (const float*)d_in[7];
  const float* gb1   = (const float*)d_in[8];
  const float* tW0   = (const float*)d_in[9];
  const float* tb0   = (const float*)d_in[10];
  const float* bng0  = (const float*)d_in[11];
  const float* bnb0  = (const float*)d_in[12];
  const float* tW1   = (const float*)d_in[13];
  const float* tb1   = (const float*)d_in[14];
  const float* bng1  = (const float*)d_in[15];
  const float* bnb1  = (const float*)d_in[16];
  const float* fc1W  = (const float*)d_in[17];
  const float* fc1b  = (const float*)d_in[18];
  const float* fc2W  = (const float*)d_in[19];
  const float* fc2b  = (const float*)d_in[20];

  float* ws   = (float*)d_ws;
  float* Hn   = ws + HN_OFF;
  float* he   = ws + HE_OFF;
  float* pre  = ws + PRE_OFF;
  float* st   = ws + STATS_OFF;
  float* Y    = ws + Y_OFF;
  float* T0   = ws + T0_OFF;
  float* T1   = ws + T1_OFF;
  float* Z0   = ws + Z0_OFF;
  float* Z1   = ws + Z1_OFF;
  float* u    = ws + U_OFF;
  float* s    = ws + S_OFF;
  float* out  = (float*)d_out;

  // zero pre + stats (contiguous 6208 floats)
  init_ws<<<25, 256, 0, stream>>>(ws + PRE_OFF, 6208);

  // ---- GNN ----
  small_mm_T<32, 32><<<24, 256, 0, stream>>>(X_n, gW0, nullptr, Y, NND);        // Y0T
  big_mm<32, 2, true, false><<<768, 256, 0, stream>>>(A, Y, gb0, T0, nullptr, NND);
  small_mm_T<32, 32><<<24, 256, 0, stream>>>(T0, gW1, nullptr, Y, NND);         // Y1T
  big_mm<32, 2, true, false><<<768, 256, 0, stream>>>(A, Y, gb1, Hn, nullptr, NND);

  // ---- HoSC layer 0 (stats fused into GEMM epilogue) ----
  small_mm_T<16, 16><<<48, 256, 0, stream>>>(X_e, tW0, tb0, T1, NED);           // Zt0T
  big_mm<16, 1, false, true><<<768, 256, 0, stream>>>(L1, T1, nullptr, T0, st, NED);
  bn_max<<<48, 256, 0, stream>>>(T0, st, bng0, bnb0, Z0, NED);

  // ---- HoSC layer 1 (rank-1 collapse: u = L1@Z0, s = L1@1) ----
  rowpass<0><<<3072, 256, 0, stream>>>(L1, Z0, nullptr, u, s, NED);
  make_zc1_stats<<<48, 256, 0, stream>>>(u, s, tW1, tb1, T1, st + 32, NED);
  bn_max<<<48, 256, 0, stream>>>(T1, st + 32, bng1, bnb1, Z1, NED);

  // ---- H_e = B1 @ [Z0 Z1] ----
  rowpass<1><<<1536, 256, 0, stream>>>(B1, Z0, Z1, he, nullptr, NED);

  // ---- head ----
  head<<<dim3(6, 64), 256, 0, stream>>>(Hn, he, fc1W, fc1b, fc2W, pre);
  final_k<<<24, 256, 0, stream>>>(pre, fc2b, out, NND);
}

// Round 4
// 631.880 us; speedup vs baseline: 1.7407x; 1.2161x over previous
//
#include <hip/hip_runtime.h>
#include <hip/hip_bf16.h>
#include <math.h>

#define NND 6144
#define NED 12288
static constexpr float EPS_BN = 1e-5f;

// ---------------- ws layout (float offsets) ----------------
#define HN_OFF    0         // [N,32] Hn
#define HE_OFF    196608    // [N,2]
#define PRE_OFF   208896    // [N]
#define STATS_OFF 215040    // [64]: sum0[16] sq0[16] | us5[5] (layer-1 collapsed stats)
#define Y_OFF     215104    // YT [32,N] (196608 floats)
#define T0_OFF    411712    // H [N,32], then Zc0 [E,16]
#define T1_OFF    608320    // ZtT [16,E]
#define Z0_OFF    804928    // [E]
#define Z1_OFF    817216    // [E]
#define U_OFF     829504    // [E]
#define S_OFF     841792    // [E]

typedef float floatx4 __attribute__((ext_vector_type(4)));

__device__ __forceinline__ float4 ntload4(const float* p) {
  floatx4 v = __builtin_nontemporal_load(reinterpret_cast<const floatx4*>(p));
  return make_float4(v.x, v.y, v.z, v.w);
}
__device__ __forceinline__ float4 ld4(const float* p) {
  return *reinterpret_cast<const float4*>(p);
}

__global__ void init_ws(float* __restrict__ p, int n) {
  int i = blockIdx.x * blockDim.x + threadIdx.x;
  if (i < n) p[i] = 0.f;
}

// CT[oc, m] = X[m,:] @ W[oc,:] (+bias). One thread per row m, transposed output.
template<int IC, int OC>
__global__ void small_mm_T(const float* __restrict__ X, const float* __restrict__ W,
                           const float* __restrict__ bias, float* __restrict__ CT, int M) {
  int m = blockIdx.x * blockDim.x + threadIdx.x;
  if (m >= M) return;
  float x[IC];
  #pragma unroll
  for (int k = 0; k < IC; k += 4) {
    float4 v = ld4(X + (size_t)m * IC + k);
    x[k] = v.x; x[k+1] = v.y; x[k+2] = v.z; x[k+3] = v.w;
  }
  #pragma unroll
  for (int oc = 0; oc < OC; ++oc) {
    float s = bias ? bias[oc] : 0.f;
    #pragma unroll
    for (int k = 0; k < IC; ++k) s = fmaf(x[k], W[oc * IC + k], s);
    CT[(size_t)oc * M + m] = s;
  }
}

// out[M,NC] = A[M,K] @ YT[NC,K]^T with LDS-staged YT panel (dedup across waves).
// block=256 (4 waves). CG col-groups of 16; RG=4/CG row-groups of 4 rows.
// k-chunk 256: lane owns k = kb + lane*4. A via nontemporal loads (stream).
template<int NC, int CG, bool RELU, bool STATS, bool DBUF>
__global__ __launch_bounds__(256, 3)
void gemm_lds(const float* __restrict__ A, const float* __restrict__ YT,
              const float* __restrict__ bias, float* __restrict__ out,
              float* __restrict__ stats, int K) {
  constexpr int RG = 4 / CG;
  constexpr int ROWS = RG * 4;
  constexpr int SF4 = NC / 4;       // stage float4s per thread
  constexpr int NB = DBUF ? 2 : 1;
  __shared__ float Yb[NB][NC][256];
  __shared__ float sst[32];

  const int tid = threadIdx.x;
  const int lane = tid & 63;
  const int w = tid >> 6;
  const int cg = w % CG, rg = w / CG;
  const int r0 = blockIdx.x * ROWS + rg * 4;
  const int c0 = cg * 16;

  const float* ap[4];
  #pragma unroll
  for (int r = 0; r < 4; ++r) ap[r] = A + (size_t)(r0 + r) * K;

  int srow[SF4], scol[SF4];
  #pragma unroll
  for (int i = 0; i < SF4; ++i) {
    int f = tid + 256 * i;
    srow[i] = f >> 6;
    scol[i] = (f & 63) * 4;
  }

  float4 sreg[SF4];
  float acc[4][16];
  #pragma unroll
  for (int r = 0; r < 4; ++r)
    #pragma unroll
    for (int c = 0; c < 16; ++c) acc[r][c] = 0.f;

  auto stage = [&](int kb) {
    #pragma unroll
    for (int i = 0; i < SF4; ++i)
      sreg[i] = ld4(YT + (size_t)srow[i] * K + kb + scol[i]);
  };
  auto dswrite = [&](int b) {
    #pragma unroll
    for (int i = 0; i < SF4; ++i)
      *reinterpret_cast<float4*>(&Yb[b][srow[i]][scol[i]]) = sreg[i];
  };
  auto compute = [&](int b, const float4* av) {
    #pragma unroll
    for (int c = 0; c < 16; ++c) {
      const float4 y = *reinterpret_cast<const float4*>(&Yb[b][c0 + c][lane * 4]);
      #pragma unroll
      for (int r = 0; r < 4; ++r) {
        acc[r][c] = fmaf(av[r].x, y.x, acc[r][c]);
        acc[r][c] = fmaf(av[r].y, y.y, acc[r][c]);
        acc[r][c] = fmaf(av[r].z, y.z, acc[r][c]);
        acc[r][c] = fmaf(av[r].w, y.w, acc[r][c]);
      }
    }
  };

  if (DBUF) {
    stage(0);
    dswrite(0);
    int cur = 0;
    for (int kb = 0; kb < K; kb += 256) {
      const bool more = (kb + 256) < K;
      if (more) stage(kb + 256);
      float4 av[4];
      #pragma unroll
      for (int r = 0; r < 4; ++r) av[r] = ntload4(ap[r] + kb + lane * 4);
      __syncthreads();
      compute(cur, av);
      if (more) dswrite(cur ^ 1);
      cur ^= 1;
    }
  } else {
    for (int kb = 0; kb < K; kb += 256) {
      stage(kb);
      float4 av[4];
      #pragma unroll
      for (int r = 0; r < 4; ++r) av[r] = ntload4(ap[r] + kb + lane * 4);
      __syncthreads();
      dswrite(0);
      __syncthreads();
      compute(0, av);
    }
  }

  // Compact cross-lane reduce: 64 values x 64 lanes -> lane l holds value l.
  float wv[64];
  #pragma unroll
  for (int r = 0; r < 4; ++r)
    #pragma unroll
    for (int c = 0; c < 16; ++c) wv[r * 16 + c] = acc[r][c];
  #pragma unroll
  for (int b = 5; b >= 0; --b) {
    const int m = 1 << b;
    const bool hi = (lane & m) != 0;
    #pragma unroll
    for (int i = 0; i < (1 << b); ++i) {
      float a  = wv[i];
      float bb = wv[i + (1 << b)];
      float send = hi ? a : bb;
      float recv = __shfl_xor(send, m, 64);
      wv[i] = (hi ? bb : a) + recv;
    }
  }

  const int rsel = lane >> 4, csel = lane & 15;
  float v = wv[0] + (bias ? bias[c0 + csel] : 0.f);
  if (RELU) v = fmaxf(v, 0.f);
  out[(size_t)(r0 + rsel) * NC + c0 + csel] = v;

  if (STATS) {
    if (tid < 32) sst[tid] = 0.f;
    __syncthreads();
    float sv = v, qv = v * v;
    sv += __shfl_xor(sv, 16, 64); sv += __shfl_xor(sv, 32, 64);
    qv += __shfl_xor(qv, 16, 64); qv += __shfl_xor(qv, 32, 64);
    if (lane < 16) { atomicAdd(&sst[csel], sv); atomicAdd(&sst[16 + csel], qv); }
    __syncthreads();
    if (tid < 32) atomicAdd(stats + tid, sst[tid]);
  }
}

// Row-dot pass over a big matrix, k-chunk 512, nontemporal matrix loads.
// MODE 0: o1[row]=M·za, o2[row]=rowsum.  MODE 1: o1[2row]=M·za, o1[2row+1]=M·zb.
template<int MODE>
__global__ __launch_bounds__(256)
void rowpass(const float* __restrict__ Mt, const float* __restrict__ za,
             const float* __restrict__ zb, float* __restrict__ o1,
             float* __restrict__ o2, int K) {
  const int lane = threadIdx.x & 63;
  const int row = blockIdx.x * 4 + (threadIdx.x >> 6);
  const float* mp = Mt + (size_t)row * K;
  float accA = 0.f, accB = 0.f;
  for (int kb = 0; kb < K; kb += 512) {
    const int k = kb + lane * 4;
    float4 a0 = ntload4(mp + k);
    float4 a1 = ntload4(mp + k + 256);
    float4 z0 = ld4(za + k);
    float4 z1 = ld4(za + k + 256);
    if (MODE == 0) {
      accA += a0.x*z0.x + a0.y*z0.y + a0.z*z0.z + a0.w*z0.w
            + a1.x*z1.x + a1.y*z1.y + a1.z*z1.z + a1.w*z1.w;
      accB += a0.x + a0.y + a0.z + a0.w + a1.x + a1.y + a1.z + a1.w;
    } else {
      float4 y0 = ld4(zb + k);
      float4 y1 = ld4(zb + k + 256);
      accA += a0.x*z0.x + a0.y*z0.y + a0.z*z0.z + a0.w*z0.w
            + a1.x*z1.x + a1.y*z1.y + a1.z*z1.z + a1.w*z1.w;
      accB += a0.x*y0.x + a0.y*y0.y + a0.z*y0.z + a0.w*y0.w
            + a1.x*y1.x + a1.y*y1.y + a1.z*y1.z + a1.w*y1.w;
    }
  }
  #pragma unroll
  for (int m = 1; m < 64; m <<= 1) {
    accA += __shfl_xor(accA, m, 64);
    accB += __shfl_xor(accB, m, 64);
  }
  if (lane == 0) {
    if (MODE == 0) { o1[row] = accA; o2[row] = accB; }
    else { o1[row * 2] = accA; o1[row * 2 + 1] = accB; }
  }
}

// Z[e] = relu(max_c(g[c]*(x-m)*rsqrt(v+eps)+beta[c]))  -- layer-0 BN+max
__global__ void bn_max(const float* __restrict__ Zc, const float* __restrict__ stats,
                       const float* __restrict__ g, const float* __restrict__ beta,
                       float* __restrict__ Z, int E) {
  const int e = blockIdx.x * blockDim.x + threadIdx.x;
  if (e >= E) return;
  const float invE = 1.f / (float)E;
  float best = -3.4e38f;
  #pragma unroll
  for (int c = 0; c < 16; ++c) {
    float m = stats[c] * invE;
    float var = stats[16 + c] * invE - m * m;
    float sc = g[c] * rsqrtf(var + EPS_BN);
    float sh = beta[c] - m * sc;
    float x = Zc[(size_t)e * 16 + c];
    best = fmaxf(best, fmaf(x, sc, sh));
  }
  Z[e] = fmaxf(best, 0.f);
}

// Layer-1 collapsed BN stats: st5 = [Σu, Σs, Σu², Σs², Σus]
__global__ void us_stats(const float* __restrict__ u, const float* __restrict__ s,
                         float* __restrict__ st5) {
  const int e = blockIdx.x * 256 + threadIdx.x;
  const int lane = threadIdx.x & 63;
  const int w = threadIdx.x >> 6;
  const float uu = u[e], ss = s[e];
  float v[5] = {uu, ss, uu * uu, ss * ss, uu * ss};
  #pragma unroll
  for (int i = 0; i < 5; ++i)
    #pragma unroll
    for (int m = 1; m < 64; m <<= 1) v[i] += __shfl_xor(v[i], m, 64);
  __shared__ float red[4][5];
  if (lane == 0) {
    #pragma unroll
    for (int i = 0; i < 5; ++i) red[w][i] = v[i];
  }
  __syncthreads();
  if (threadIdx.x < 5) {
    float t = red[0][threadIdx.x] + red[1][threadIdx.x] + red[2][threadIdx.x] + red[3][threadIdx.x];
    atomicAdd(st5 + threadIdx.x, t);
  }
}

// Z1 directly from (u,s): Zc1[e,c] = W1[c]u + b1[c]s, BN via collapsed stats.
__global__ void z1_from_us(const float* __restrict__ u, const float* __restrict__ s,
                           const float* __restrict__ st5,
                           const float* __restrict__ W1, const float* __restrict__ b1,
                           const float* __restrict__ g, const float* __restrict__ beta,
                           float* __restrict__ Z1, int E) {
  const int e = blockIdx.x * blockDim.x + threadIdx.x;
  if (e >= E) return;
  const float invE = 1.f / (float)E;
  const float Su = st5[0], Ss = st5[1], Suu = st5[2], Sss = st5[3], Sus = st5[4];
  const float uu = u[e], ssv = s[e];
  float best = -3.4e38f;
  #pragma unroll
  for (int c = 0; c < 16; ++c) {
    const float wc = W1[c], bc = b1[c];
    const float mean = (wc * Su + bc * Ss) * invE;
    const float ex2 = (wc * wc * Suu + 2.f * wc * bc * Sus + bc * bc * Sss) * invE;
    const float var = ex2 - mean * mean;
    const float sc = g[c] * rsqrtf(var + EPS_BN);
    const float sh = beta[c] - mean * sc;
    best = fmaxf(best, fmaf(wc * uu + bc * ssv, sc, sh));
  }
  Z1[e] = fmaxf(best, 0.f);
}

// pre[n] += sum_{j in chunk} relu(Hcat[n]·fc1W[j] + fc1b[j]) * fc2W[j]
__global__ __launch_bounds__(256, 2)
void head(const float* __restrict__ Hn, const float* __restrict__ he,
          const float* __restrict__ W1, const float* __restrict__ b1,
          const float* __restrict__ w2, float* __restrict__ pre) {
  const int t = threadIdx.x;
  const int nb = blockIdx.x;      // 6 blocks of 1024 rows
  const int jb = blockIdx.y;      // 64 chunks of 192 j
  int n[4];
  float h[4][34];
  float acc[4] = {0.f, 0.f, 0.f, 0.f};
  #pragma unroll
  for (int i = 0; i < 4; ++i) {
    n[i] = nb * 1024 + i * 256 + t;
    #pragma unroll
    for (int k = 0; k < 32; k += 4) {
      float4 v = ld4(Hn + (size_t)n[i] * 32 + k);
      h[i][k] = v.x; h[i][k+1] = v.y; h[i][k+2] = v.z; h[i][k+3] = v.w;
    }
    h[i][32] = he[n[i] * 2];
    h[i][33] = he[n[i] * 2 + 1];
  }
  const int j0 = jb * 192;
  for (int j = j0; j < j0 + 192; ++j) {
    const float* wp = W1 + (size_t)j * 34;
    const float bj = b1[j], vj = w2[j];
    float s0 = bj, s1 = bj, s2 = bj, s3 = bj;
    #pragma unroll
    for (int k = 0; k < 34; ++k) {
      const float wk = wp[k];
      s0 = fmaf(h[0][k], wk, s0); s1 = fmaf(h[1][k], wk, s1);
      s2 = fmaf(h[2][k], wk, s2); s3 = fmaf(h[3][k], wk, s3);
    }
    acc[0] += fmaxf(s0, 0.f) * vj;
    acc[1] += fmaxf(s1, 0.f) * vj;
    acc[2] += fmaxf(s2, 0.f) * vj;
    acc[3] += fmaxf(s3, 0.f) * vj;
  }
  #pragma unroll
  for (int i = 0; i < 4; ++i) atomicAdd(pre + n[i], acc[i]);
}

__global__ void final_k(const float* __restrict__ pre, const float* __restrict__ b2,
                        float* __restrict__ out, int Nn) {
  const int i = blockIdx.x * blockDim.x + threadIdx.x;
  if (i < Nn) out[i] = 1.f / (1.f + expf(-(pre[i] + b2[0])));
}

extern "C" void kernel_launch(void* const* d_in, const int* in_sizes, int n_in,
                              void* d_out, int out_size, void* d_ws, size_t ws_size,
                              hipStream_t stream) {
  const float* X_n   = (const float*)d_in[0];
  const float* X_e   = (const float*)d_in[1];
  const float* A     = (const float*)d_in[2];
  const float* L1    = (const float*)d_in[3];
  const float* B1    = (const float*)d_in[4];
  const float* gW0   = (const float*)d_in[5];
  const float* gb0   = (const float*)d_in[6];
  const float* gW1   = (const float*)d_in[7];
  const float* gb1   = (const float*)d_in[8];
  const float* tW0   = (const float*)d_in[9];
  const float* tb0   = (const float*)d_in[10];
  const float* bng0  = (const float*)d_in[11];
  const float* bnb0  = (const float*)d_in[12];
  const float* tW1   = (const float*)d_in[13];
  const float* tb1   = (const float*)d_in[14];
  const float* bng1  = (const float*)d_in[15];
  const float* bnb1  = (const float*)d_in[16];
  const float* fc1W  = (const float*)d_in[17];
  const float* fc1b  = (const float*)d_in[18];
  const float* fc2W  = (const float*)d_in[19];
  const float* fc2b  = (const float*)d_in[20];

  float* ws   = (float*)d_ws;
  float* Hn   = ws + HN_OFF;
  float* he   = ws + HE_OFF;
  float* pre  = ws + PRE_OFF;
  float* st   = ws + STATS_OFF;
  float* Y    = ws + Y_OFF;
  float* T0   = ws + T0_OFF;
  float* T1   = ws + T1_OFF;
  float* Z0   = ws + Z0_OFF;
  float* Z1   = ws + Z1_OFF;
  float* u    = ws + U_OFF;
  float* s    = ws + S_OFF;
  float* out  = (float*)d_out;

  // zero pre (6144) + stats (64, incl. us5 at +32)
  init_ws<<<25, 256, 0, stream>>>(ws + PRE_OFF, 6208);

  // ---- GNN ----
  small_mm_T<32, 32><<<24, 256, 0, stream>>>(X_n, gW0, nullptr, Y, NND);          // Y0T
  gemm_lds<32, 2, true, false, false><<<768, 256, 0, stream>>>(A, Y, gb0, T0, nullptr, NND);
  small_mm_T<32, 32><<<24, 256, 0, stream>>>(T0, gW1, nullptr, Y, NND);           // Y1T
  gemm_lds<32, 2, true, false, false><<<768, 256, 0, stream>>>(A, Y, gb1, Hn, nullptr, NND);

  // ---- HoSC layer 0 (stats fused into GEMM epilogue) ----
  small_mm_T<16, 16><<<48, 256, 0, stream>>>(X_e, tW0, tb0, T1, NED);             // Zt0T
  gemm_lds<16, 1, false, true, true><<<768, 256, 0, stream>>>(L1, T1, nullptr, T0, st, NED);
  bn_max<<<48, 256, 0, stream>>>(T0, st, bng0, bnb0, Z0, NED);

  // ---- HoSC layer 1 (rank-1 collapse; BN stats collapse to 5 scalars) ----
  rowpass<0><<<3072, 256, 0, stream>>>(L1, Z0, nullptr, u, s, NED);
  us_stats<<<48, 256, 0, stream>>>(u, s, st + 32);
  z1_from_us<<<48, 256, 0, stream>>>(u, s, st + 32, tW1, tb1, bng1, bnb1, Z1, NED);

  // ---- H_e = B1 @ [Z0 Z1] ----
  rowpass<1><<<1536, 256, 0, stream>>>(B1, Z0, Z1, he, nullptr, NED);

  // ---- head ----
  head<<<dim3(6, 64), 256, 0, stream>>>(Hn, he, fc1W, fc1b, fc2W, pre);
  final_k<<<24, 256, 0, stream>>>(pre, fc2b, out, NND);
}

// Round 5
// 610.535 us; speedup vs baseline: 1.8016x; 1.0350x over previous
//
#include <hip/hip_runtime.h>
#include <hip/hip_bf16.h>
#include <math.h>

#define NND 6144
#define NED 12288
static constexpr float EPS_BN = 1e-5f;

// ---------------- ws layout (float offsets) ----------------
#define HN_OFF    0         // [N,32] Hn
#define HE_OFF    196608    // [N,2]
#define ST_OFF    208896    // [64]: sum0[16] sq0[16] | us5[5]
#define Y_OFF     208960    // YT [32,N]
#define T0_OFF    405568    // H [N,32], then Zc0 [E,16]
#define T1_OFF    602176    // ZtT [16,E]
#define Z0_OFF    798784    // [E]
#define Z1_OFF    811072    // [E]
#define U_OFF     823360    // [E]
#define S_OFF     835648    // [E]
#define PP_OFF    847936    // head partials [64][N]

typedef float floatx4 __attribute__((ext_vector_type(4)));

__device__ __forceinline__ float4 ntload4(const float* p) {
  floatx4 v = __builtin_nontemporal_load(reinterpret_cast<const floatx4*>(p));
  return make_float4(v.x, v.y, v.z, v.w);
}
__device__ __forceinline__ float4 ld4(const float* p) {
  return *reinterpret_cast<const float4*>(p);
}

__global__ void init_ws(float* __restrict__ p, int n) {
  int i = blockIdx.x * blockDim.x + threadIdx.x;
  if (i < n) p[i] = 0.f;
}

// CT[oc, m] = X[m,:] @ W[oc,:] (+bias). One thread per row m, transposed output.
template<int IC, int OC>
__global__ void small_mm_T(const float* __restrict__ X, const float* __restrict__ W,
                           const float* __restrict__ bias, float* __restrict__ CT, int M) {
  int m = blockIdx.x * blockDim.x + threadIdx.x;
  if (m >= M) return;
  float x[IC];
  #pragma unroll
  for (int k = 0; k < IC; k += 4) {
    float4 v = ld4(X + (size_t)m * IC + k);
    x[k] = v.x; x[k+1] = v.y; x[k+2] = v.z; x[k+3] = v.w;
  }
  #pragma unroll
  for (int oc = 0; oc < OC; ++oc) {
    float s = bias ? bias[oc] : 0.f;
    #pragma unroll
    for (int k = 0; k < IC; ++k) s = fmaf(x[k], W[oc * IC + k], s);
    CT[(size_t)oc * M + m] = s;
  }
}

// out[M,NC] = A[M,K] @ YT[NC,K]^T, LDS-staged YT + register-double-buffered A.
// block=256 (4 waves). CG col-groups of 16; ROWS=(4/CG)*4 rows per block.
// Chunk 256 k: both A-loads and YT-stage loads for chunk k+1 are issued while
// chunk k computes -> HBM latency hidden under ~512 VALU cycles.
template<int NC, int CG, bool RELU, bool STATS, bool NT>
__global__ __launch_bounds__(256, 3)
void gemm_lds(const float* __restrict__ A, const float* __restrict__ YT,
              const float* __restrict__ bias, float* __restrict__ out,
              float* __restrict__ stats, int K) {
  constexpr int RG = 4 / CG;
  constexpr int ROWS = RG * 4;
  constexpr int SF4 = NC / 4;       // staged float4s per thread
  __shared__ float Yb[NC][256];
  __shared__ float sst[32];

  const int tid = threadIdx.x;
  const int lane = tid & 63;
  const int w = tid >> 6;
  const int cg = w % CG, rg = w / CG;
  const int r0 = blockIdx.x * ROWS + rg * 4;
  const int c0 = cg * 16;

  const float* ap[4];
  #pragma unroll
  for (int r = 0; r < 4; ++r) ap[r] = A + (size_t)(r0 + r) * K;

  int srow[SF4], scol[SF4];
  #pragma unroll
  for (int i = 0; i < SF4; ++i) {
    int f = tid + 256 * i;
    srow[i] = f >> 6;
    scol[i] = (f & 63) * 4;
  }

  float4 sreg[SF4], av[4], av2[4];
  float acc[4][16];
  #pragma unroll
  for (int r = 0; r < 4; ++r)
    #pragma unroll
    for (int c = 0; c < 16; ++c) acc[r][c] = 0.f;

  auto stage = [&](int kb) {
    #pragma unroll
    for (int i = 0; i < SF4; ++i)
      sreg[i] = ld4(YT + (size_t)srow[i] * K + kb + scol[i]);
  };
  auto loadA = [&](int kb, float4* dst) {
    #pragma unroll
    for (int r = 0; r < 4; ++r)
      dst[r] = NT ? ntload4(ap[r] + kb + lane * 4) : ld4(ap[r] + kb + lane * 4);
  };

  // prologue: issue chunk-0 loads
  stage(0);
  loadA(0, av2);

  for (int kb = 0; kb < K; kb += 256) {
    __syncthreads();                 // previous compute done reading Yb
    #pragma unroll
    for (int i = 0; i < SF4; ++i)    // write staged chunk (waits its loads)
      *reinterpret_cast<float4*>(&Yb[srow[i]][scol[i]]) = sreg[i];
    #pragma unroll
    for (int r = 0; r < 4; ++r) av[r] = av2[r];
    if (kb + 256 < K) {              // issue next chunk's loads NOW
      stage(kb + 256);
      loadA(kb + 256, av2);
    }
    __syncthreads();                 // Yb visible
    #pragma unroll
    for (int c = 0; c < 16; ++c) {
      const float4 y = *reinterpret_cast<const float4*>(&Yb[c0 + c][lane * 4]);
      #pragma unroll
      for (int r = 0; r < 4; ++r) {
        acc[r][c] = fmaf(av[r].x, y.x, acc[r][c]);
        acc[r][c] = fmaf(av[r].y, y.y, acc[r][c]);
        acc[r][c] = fmaf(av[r].z, y.z, acc[r][c]);
        acc[r][c] = fmaf(av[r].w, y.w, acc[r][c]);
      }
    }
  }

  // Compact cross-lane reduce: 64 values x 64 lanes -> lane l holds value l.
  float wv[64];
  #pragma unroll
  for (int r = 0; r < 4; ++r)
    #pragma unroll
    for (int c = 0; c < 16; ++c) wv[r * 16 + c] = acc[r][c];
  #pragma unroll
  for (int b = 5; b >= 0; --b) {
    const int m = 1 << b;
    const bool hi = (lane & m) != 0;
    #pragma unroll
    for (int i = 0; i < (1 << b); ++i) {
      float a  = wv[i];
      float bb = wv[i + (1 << b)];
      float send = hi ? a : bb;
      float recv = __shfl_xor(send, m, 64);
      wv[i] = (hi ? bb : a) + recv;
    }
  }

  const int rsel = lane >> 4, csel = lane & 15;
  float v = wv[0] + (bias ? bias[c0 + csel] : 0.f);
  if (RELU) v = fmaxf(v, 0.f);
  out[(size_t)(r0 + rsel) * NC + c0 + csel] = v;

  if (STATS) {
    if (tid < 32) sst[tid] = 0.f;
    __syncthreads();
    float sv = v, qv = v * v;
    sv += __shfl_xor(sv, 16, 64); sv += __shfl_xor(sv, 32, 64);
    qv += __shfl_xor(qv, 16, 64); qv += __shfl_xor(qv, 32, 64);
    if (lane < 16) { atomicAdd(&sst[csel], sv); atomicAdd(&sst[16 + csel], qv); }
    __syncthreads();
    if (tid < 32) atomicAdd(stats + tid, sst[tid]);
  }
}

// Row-dot pass over a big streamed matrix, chunk 512, depth-1 prefetch.
// MODE 0: o1[row]=M·za, o2[row]=rowsum.  MODE 1: o1[2row]=M·za, o1[2row+1]=M·zb.
template<int MODE>
__global__ __launch_bounds__(256)
void rowpass(const float* __restrict__ Mt, const float* __restrict__ za,
             const float* __restrict__ zb, float* __restrict__ o1,
             float* __restrict__ o2, int K) {
  const int lane = threadIdx.x & 63;
  const int row = blockIdx.x * 4 + (threadIdx.x >> 6);
  const float* mp = Mt + (size_t)row * K;
  float accA = 0.f, accB = 0.f;
  float4 a0 = ntload4(mp + lane * 4);
  float4 a1 = ntload4(mp + 256 + lane * 4);
  for (int kb = 0; kb < K; kb += 512) {
    const int k = kb + lane * 4;
    float4 n0, n1;
    const bool more = (kb + 512) < K;
    if (more) {
      n0 = ntload4(mp + k + 512);
      n1 = ntload4(mp + k + 768);
    }
    float4 z0 = ld4(za + k);
    float4 z1 = ld4(za + k + 256);
    if (MODE == 0) {
      accA += a0.x*z0.x + a0.y*z0.y + a0.z*z0.z + a0.w*z0.w
            + a1.x*z1.x + a1.y*z1.y + a1.z*z1.z + a1.w*z1.w;
      accB += a0.x + a0.y + a0.z + a0.w + a1.x + a1.y + a1.z + a1.w;
    } else {
      float4 y0 = ld4(zb + k);
      float4 y1 = ld4(zb + k + 256);
      accA += a0.x*z0.x + a0.y*z0.y + a0.z*z0.z + a0.w*z0.w
            + a1.x*z1.x + a1.y*z1.y + a1.z*z1.z + a1.w*z1.w;
      accB += a0.x*y0.x + a0.y*y0.y + a0.z*y0.z + a0.w*y0.w
            + a1.x*y1.x + a1.y*y1.y + a1.z*y1.z + a1.w*y1.w;
    }
    if (more) { a0 = n0; a1 = n1; }
  }
  #pragma unroll
  for (int m = 1; m < 64; m <<= 1) {
    accA += __shfl_xor(accA, m, 64);
    accB += __shfl_xor(accB, m, 64);
  }
  if (lane == 0) {
    if (MODE == 0) { o1[row] = accA; o2[row] = accB; }
    else { o1[row * 2] = accA; o1[row * 2 + 1] = accB; }
  }
}

// Z[e] = relu(max_c(g[c]*(x-m)*rsqrt(v+eps)+beta[c]))  -- layer-0 BN+max
__global__ void bn_max(const float* __restrict__ Zc, const float* __restrict__ stats,
                       const float* __restrict__ g, const float* __restrict__ beta,
                       float* __restrict__ Z, int E) {
  const int e = blockIdx.x * blockDim.x + threadIdx.x;
  if (e >= E) return;
  const float invE = 1.f / (float)E;
  float best = -3.4e38f;
  #pragma unroll
  for (int c = 0; c < 16; ++c) {
    float m = stats[c] * invE;
    float var = stats[16 + c] * invE - m * m;
    float sc = g[c] * rsqrtf(var + EPS_BN);
    float sh = beta[c] - m * sc;
    float x = Zc[(size_t)e * 16 + c];
    best = fmaxf(best, fmaf(x, sc, sh));
  }
  Z[e] = fmaxf(best, 0.f);
}

// Layer-1 collapsed BN stats: st5 = [Σu, Σs, Σu², Σs², Σus]
__global__ void us_stats(const float* __restrict__ u, const float* __restrict__ s,
                         float* __restrict__ st5) {
  const int e = blockIdx.x * 256 + threadIdx.x;
  const int lane = threadIdx.x & 63;
  const int w = threadIdx.x >> 6;
  const float uu = u[e], ss = s[e];
  float v[5] = {uu, ss, uu * uu, ss * ss, uu * ss};
  #pragma unroll
  for (int i = 0; i < 5; ++i)
    #pragma unroll
    for (int m = 1; m < 64; m <<= 1) v[i] += __shfl_xor(v[i], m, 64);
  __shared__ float red[4][5];
  if (lane == 0) {
    #pragma unroll
    for (int i = 0; i < 5; ++i) red[w][i] = v[i];
  }
  __syncthreads();
  if (threadIdx.x < 5) {
    float t = red[0][threadIdx.x] + red[1][threadIdx.x] + red[2][threadIdx.x] + red[3][threadIdx.x];
    atomicAdd(st5 + threadIdx.x, t);
  }
}

// Z1 directly from (u,s): Zc1[e,c] = W1[c]u + b1[c]s, BN via collapsed stats.
__global__ void z1_from_us(const float* __restrict__ u, const float* __restrict__ s,
                           const float* __restrict__ st5,
                           const float* __restrict__ W1, const float* __restrict__ b1,
                           const float* __restrict__ g, const float* __restrict__ beta,
                           float* __restrict__ Z1, int E) {
  const int e = blockIdx.x * blockDim.x + threadIdx.x;
  if (e >= E) return;
  const float invE = 1.f / (float)E;
  const float Su = st5[0], Ss = st5[1], Suu = st5[2], Sss = st5[3], Sus = st5[4];
  const float uu = u[e], ssv = s[e];
  float best = -3.4e38f;
  #pragma unroll
  for (int c = 0; c < 16; ++c) {
    const float wc = W1[c], bc = b1[c];
    const float mean = (wc * Su + bc * Ss) * invE;
    const float ex2 = (wc * wc * Suu + 2.f * wc * bc * Sus + bc * bc * Sss) * invE;
    const float var = ex2 - mean * mean;
    const float sc = g[c] * rsqrtf(var + EPS_BN);
    const float sh = beta[c] - mean * sc;
    best = fmaxf(best, fmaf(wc * uu + bc * ssv, sc, sh));
  }
  Z1[e] = fmaxf(best, 0.f);
}

// prepart[jb][n] = sum_{j in chunk jb} relu(Hcat[n]·fc1W[j] + fc1b[j]) * fc2W[j]
// grid (8, 64) = 512 blocks (exactly 2/CU), 3 rows/thread, NO atomics.
__global__ __launch_bounds__(256, 2)
void head(const float* __restrict__ Hn, const float* __restrict__ he,
          const float* __restrict__ W1, const float* __restrict__ b1,
          const float* __restrict__ w2, float* __restrict__ prepart) {
  const int t = threadIdx.x;
  const int nb = blockIdx.x;      // 8 blocks of 768 rows
  const int jb = blockIdx.y;      // 64 chunks of 192 j
  int n[3];
  float h[3][34];
  float acc[3] = {0.f, 0.f, 0.f};
  #pragma unroll
  for (int i = 0; i < 3; ++i) {
    n[i] = nb * 768 + i * 256 + t;
    #pragma unroll
    for (int k = 0; k < 32; k += 4) {
      float4 v = ld4(Hn + (size_t)n[i] * 32 + k);
      h[i][k] = v.x; h[i][k+1] = v.y; h[i][k+2] = v.z; h[i][k+3] = v.w;
    }
    float2 e2 = *reinterpret_cast<const float2*>(he + n[i] * 2);
    h[i][32] = e2.x;
    h[i][33] = e2.y;
  }
  const int j0 = jb * 192;
  for (int j = j0; j < j0 + 192; ++j) {
    const float* wp = W1 + (size_t)j * 34;
    const float bj = b1[j], vj = w2[j];
    float s0 = bj, s1 = bj, s2 = bj;
    #pragma unroll
    for (int k = 0; k < 34; ++k) {
      const float wk = wp[k];
      s0 = fmaf(h[0][k], wk, s0);
      s1 = fmaf(h[1][k], wk, s1);
      s2 = fmaf(h[2][k], wk, s2);
    }
    acc[0] += fmaxf(s0, 0.f) * vj;
    acc[1] += fmaxf(s1, 0.f) * vj;
    acc[2] += fmaxf(s2, 0.f) * vj;
  }
  #pragma unroll
  for (int i = 0; i < 3; ++i) prepart[(size_t)jb * NND + n[i]] = acc[i];
}

__global__ void final_k(const float* __restrict__ pp, const float* __restrict__ b2,
                        float* __restrict__ out, int Nn) {
  const int i = blockIdx.x * blockDim.x + threadIdx.x;
  if (i >= Nn) return;
  float s = 0.f;
  #pragma unroll
  for (int j = 0; j < 64; ++j) s += pp[(size_t)j * NND + i];
  out[i] = 1.f / (1.f + expf(-(s + b2[0])));
}

extern "C" void kernel_launch(void* const* d_in, const int* in_sizes, int n_in,
                              void* d_out, int out_size, void* d_ws, size_t ws_size,
                              hipStream_t stream) {
  const float* X_n   = (const float*)d_in[0];
  const float* X_e   = (const float*)d_in[1];
  const float* A     = (const float*)d_in[2];
  const float* L1    = (const float*)d_in[3];
  const float* B1    = (const float*)d_in[4];
  const float* gW0   = (const float*)d_in[5];
  const float* gb0   = (const float*)d_in[6];
  const float* gW1   = (const float*)d_in[7];
  const float* gb1   = (const float*)d_in[8];
  const float* tW0   = (const float*)d_in[9];
  const float* tb0   = (const float*)d_in[10];
  const float* bng0  = (const float*)d_in[11];
  const float* bnb0  = (const float*)d_in[12];
  const float* tW1   = (const float*)d_in[13];
  const float* tb1   = (const float*)d_in[14];
  const float* bng1  = (const float*)d_in[15];
  const float* bnb1  = (const float*)d_in[16];
  const float* fc1W  = (const float*)d_in[17];
  const float* fc1b  = (const float*)d_in[18];
  const float* fc2W  = (const float*)d_in[19];
  const float* fc2b  = (const float*)d_in[20];

  float* ws   = (float*)d_ws;
  float* Hn   = ws + HN_OFF;
  float* he   = ws + HE_OFF;
  float* st   = ws + ST_OFF;
  float* Y    = ws + Y_OFF;
  float* T0   = ws + T0_OFF;
  float* T1   = ws + T1_OFF;
  float* Z0   = ws + Z0_OFF;
  float* Z1   = ws + Z1_OFF;
  float* u    = ws + U_OFF;
  float* s    = ws + S_OFF;
  float* pp   = ws + PP_OFF;
  float* out  = (float*)d_out;

  // zero the atomic stats area (64 floats) every call
  init_ws<<<1, 64, 0, stream>>>(st, 64);

  // ---- GNN (A cached: no nt -> 2nd pass hits L3) ----
  small_mm_T<32, 32><<<24, 256, 0, stream>>>(X_n, gW0, nullptr, Y, NND);          // Y0T
  gemm_lds<32, 2, true, false, false><<<768, 256, 0, stream>>>(A, Y, gb0, T0, nullptr, NND);
  small_mm_T<32, 32><<<24, 256, 0, stream>>>(T0, gW1, nullptr, Y, NND);           // Y1T
  gemm_lds<32, 2, true, false, false><<<768, 256, 0, stream>>>(A, Y, gb1, Hn, nullptr, NND);

  // ---- HoSC layer 0 (stats fused into GEMM epilogue; L1 streamed nt) ----
  small_mm_T<16, 16><<<48, 256, 0, stream>>>(X_e, tW0, tb0, T1, NED);             // Zt0T
  gemm_lds<16, 1, false, true, true><<<768, 256, 0, stream>>>(L1, T1, nullptr, T0, st, NED);
  bn_max<<<48, 256, 0, stream>>>(T0, st, bng0, bnb0, Z0, NED);

  // ---- HoSC layer 1 (rank-1 collapse; BN stats collapse to 5 scalars) ----
  rowpass<0><<<3072, 256, 0, stream>>>(L1, Z0, nullptr, u, s, NED);
  us_stats<<<48, 256, 0, stream>>>(u, s, st + 32);
  z1_from_us<<<48, 256, 0, stream>>>(u, s, st + 32, tW1, tb1, bng1, bnb1, Z1, NED);

  // ---- H_e = B1 @ [Z0 Z1] ----
  rowpass<1><<<1536, 256, 0, stream>>>(B1, Z0, Z1, he, nullptr, NED);

  // ---- head (no atomics: per-jb partials, then reduce) ----
  head<<<dim3(8, 64), 256, 0, stream>>>(Hn, he, fc1W, fc1b, fc2W, pp);
  final_k<<<24, 256, 0, stream>>>(pp, fc2b, out, NND);
}